// Round 7
// baseline (7726.967 us; speedup 1.0000x reference)
//
#include <hip/hip_runtime.h>
#include <stdint.h>

#define NBATCH 32
#define NPTS   65536
#define MCENT  2048
#define BPB    8                 // blocks per batch
#define THREADS 1024
#define CHUNK  (NPTS / BPB)      // 8192 points per block
#define WPT    (CHUNK / THREADS) // 8 points per thread

__device__ __forceinline__ float f_from_bits(uint32_t u) {
    union { uint32_t u; float f; } c; c.u = u; return c.f;
}
__device__ __forceinline__ uint32_t bits_from_f(float f) {
    union { float f; uint32_t u; } c; c.f = f; return c.u;
}

// Slot layout in d_ws: [2 parities][NBATCH][BPB], each padded to 64B (8 ull).
// slot value: [63:32]=float bits of partial max, [31:16]=iteration tag,
// [15:0]=local point index within chunk. Poison 0xAA.. gives tag 0xAAAA
// which never matches k in [1,2047] (zeroed ws gives tag 0 — also safe), so
// no init pass is needed. Protocol: a block can only publish iter k+1 after
// seeing all 8 iter-k tags, so parity double-buffering is race-free.

__global__ __launch_bounds__(THREADS, 1) void fps_kernel(
    const float* __restrict__ xyz,      // [NBATCH, NPTS, 3] fp32 (raw)
    float* __restrict__ out,            // [NBATCH, MCENT, 3] fp32
    unsigned long long* __restrict__ slots)
{
    const int t = threadIdx.x;
    const int b = blockIdx.x >> 3;   // batch
    const int j = blockIdx.x & 7;    // block-within-batch
    const float* base = xyz + (size_t)b * NPTS * 3;
    const int p0 = j * CHUNK;

    // coords + running min-dist live in registers
    float x[WPT], y[WPT], z[WPT], d[WPT];
#pragma unroll
    for (int w = 0; w < WPT; ++w) {
        const int p = p0 + w * THREADS + t;
        x[w] = base[(size_t)p * 3 + 0];
        y[w] = base[(size_t)p * 3 + 1];
        z[w] = base[(size_t)p * 3 + 2];
        d[w] = 1e10f;
    }

    __shared__ float ldsC[4];     // broadcast center
    __shared__ float wv[16];      // per-wave partial max value
    __shared__ int   wi[16];      // per-wave partial argmax (local idx)

    if (t == 0) {
        // initial center = point 0 of the batch
        const float cx = base[0], cy = base[1], cz = base[2];
        ldsC[0] = cx; ldsC[1] = cy; ldsC[2] = cz;
        if (j == 0) {
            float* o = out + (size_t)b * MCENT * 3;
            o[0] = cx; o[1] = cy; o[2] = cz;
        }
    }

    const int wave = t >> 6;
    const int lane = t & 63;

    for (int k = 1; k < MCENT; ++k) {
        __syncthreads();                         // ldsC valid for this iter
        const float cx = ldsC[0], cy = ldsC[1], cz = ldsC[2];

        float bv = -1.0f; int bp = 0;
#pragma unroll
        for (int w = 0; w < WPT; ++w) {
            // LLVM fadd-contraction convention (XLA CPU/GPU backends):
            //   a1 = dx^2 + dy^2  -> fma(dx,dx, mul(dy,dy))   (dy^2 rounded,
            //                                                  dx^2 exact)
            //   a2 = a1 + dz^2    -> fma(dz,dz, a1)
            const float dx = __fsub_rn(x[w], cx);
            const float dy = __fsub_rn(y[w], cy);
            const float dz = __fsub_rn(z[w], cz);
            const float s  = __fmaf_rn(dz, dz,
                             __fmaf_rn(dx, dx,
                             __fmul_rn(dy, dy)));
            const float nd = fminf(d[w], s);
            d[w] = nd;
            // strict > keeps smallest local index (w ascending)
            if (nd > bv) { bv = nd; bp = w * THREADS + t; }
        }

        // wave-level argmax (64 lanes), tie -> smaller index
#pragma unroll
        for (int off = 32; off >= 1; off >>= 1) {
            const float ov = __shfl_down(bv, off);
            const int   oi = __shfl_down(bp, off);
            if (ov > bv || (ov == bv && oi < bp)) { bv = ov; bp = oi; }
        }
        if (lane == 0) { wv[wave] = bv; wi[wave] = bp; }
        __syncthreads();

        if (t == 0) {
            // cross-wave reduce, tie -> smaller index
            float pv = wv[0]; int pi = wi[0];
            for (int w2 = 1; w2 < 16; ++w2) {
                const float v2 = wv[w2]; const int i2 = wi[w2];
                if (v2 > pv || (v2 == pv && i2 < pi)) { pv = v2; pi = i2; }
            }
            // publish partial (value | tag | local idx); payload entirely
            // inside the 64-bit atomic word, so relaxed agent-scope is enough
            const unsigned long long pk =
                ((unsigned long long)bits_from_f(pv) << 32) |
                ((unsigned)k << 16) | (unsigned)pi;
            unsigned long long* sl =
                slots + (size_t)(k & 1) * (NBATCH * BPB * 8) + (size_t)b * (BPB * 8);
            __hip_atomic_store(&sl[j * 8], pk,
                               __ATOMIC_RELAXED, __HIP_MEMORY_SCOPE_AGENT);

            // spin until all 8 partials for this iteration are visible
            unsigned long long got[BPB];
            bool ok;
            do {
                ok = true;
#pragma unroll
                for (int jj = 0; jj < BPB; ++jj)
                    got[jj] = __hip_atomic_load(&sl[jj * 8],
                                                __ATOMIC_RELAXED,
                                                __HIP_MEMORY_SCOPE_AGENT);
#pragma unroll
                for (int jj = 0; jj < BPB; ++jj)
                    ok &= (((unsigned)(got[jj] & 0xffffffffull)) >> 16) == (unsigned)k;
                if (!ok) __builtin_amdgcn_s_sleep(1);
            } while (!ok);

            // global winner; jj ascending + strict > keeps smallest batch-global idx
            float gv = -1.0f; int gidx = 0;
#pragma unroll
            for (int jj = 0; jj < BPB; ++jj) {
                const float v = f_from_bits((uint32_t)(got[jj] >> 32));
                const int   i = jj * CHUNK + (int)(got[jj] & 0xffffull);
                if (v > gv || (v == gv && i < gidx)) { gv = v; gidx = i; }
            }

            // fetch winner coords (raw fp32) from the read-only input
            const float nx = base[(size_t)gidx * 3 + 0];
            const float ny = base[(size_t)gidx * 3 + 1];
            const float nz = base[(size_t)gidx * 3 + 2];
            ldsC[0] = nx; ldsC[1] = ny; ldsC[2] = nz;
            if (j == 0) {
                float* o = out + ((size_t)b * MCENT + k) * 3;
                o[0] = nx; o[1] = ny; o[2] = nz;
            }
        }
    }
}

extern "C" void kernel_launch(void* const* d_in, const int* in_sizes, int n_in,
                              void* d_out, int out_size, void* d_ws, size_t ws_size,
                              hipStream_t stream) {
    const float* xyz = (const float*)d_in[0];
    float* out = (float*)d_out;
    unsigned long long* slots = (unsigned long long*)d_ws; // needs 32 KiB

    fps_kernel<<<dim3(NBATCH * BPB), dim3(THREADS), 0, stream>>>(xyz, out, slots);
}

// Round 8
// 6430.428 us; speedup vs baseline: 1.2016x; 1.2016x over previous
//
#include <hip/hip_runtime.h>
#include <stdint.h>

#define NBATCH 32
#define NPTS   65536
#define MCENT  2048
#define BPB    8                 // blocks per batch
#define THREADS 1024
#define CHUNK  (NPTS / BPB)      // 8192 points per block
#define WPT    (CHUNK / THREADS) // 8 points per thread
#define SLOT_ULL 8               // 64B-padded slot; words 0..3 = val,x,y,z

static __device__ __forceinline__ float f_from_bits(uint32_t u) {
    union { uint32_t u; float f; } c; c.u = u; return c.f;
}
static __device__ __forceinline__ uint32_t bits_from_f(float f) {
    union { float f; uint32_t u; } c; c.f = f; return c.u;
}
// tagged word: [63:32]=payload bits, [31:16]=iteration k, [15:0]=local idx
static __device__ __forceinline__ unsigned long long packw(uint32_t hi, int k, int pi) {
    return ((unsigned long long)hi << 32) | ((unsigned)k << 16) | (unsigned)pi;
}

// d_ws slots: [2 parities][NBATCH][BPB] x 64B. Each of the 4 used words is
// independently tagged with k, so publishes are 4 parallel relaxed stores
// (no release/acquire, no ordering) and a reader accepts a word only when
// its own tag matches. Poison 0xAA.. -> tag 0xAAAA, zero -> 0: neither
// matches k in [1,2047], so no init pass. Parity reuse is safe: a block
// overwrites its parity-p slot at k+2 only after seeing all k+1 tags, which
// requires every peer to have finished its k-round reads (values banked in
// registers by the poll itself).

__global__ __launch_bounds__(THREADS, 1) void fps_kernel(
    const float* __restrict__ xyz,      // [NBATCH, NPTS, 3] fp32
    float* __restrict__ out,            // [NBATCH, MCENT, 3] fp32
    unsigned long long* __restrict__ slots)
{
    const int t = threadIdx.x;
    const int b = blockIdx.x >> 3;   // batch
    const int j = blockIdx.x & 7;    // block-within-batch
    const float* base = xyz + (size_t)b * NPTS * 3;
    const int p0 = j * CHUNK;

    // coords + running min-dist live in registers
    float x[WPT], y[WPT], z[WPT], d[WPT];
#pragma unroll
    for (int w = 0; w < WPT; ++w) {
        const int p = p0 + w * THREADS + t;
        x[w] = base[(size_t)p * 3 + 0];
        y[w] = base[(size_t)p * 3 + 1];
        z[w] = base[(size_t)p * 3 + 2];
        d[w] = 1e10f;
    }

    __shared__ float ldsC[4];     // broadcast center
    __shared__ float wv[16];      // per-wave partial max value
    __shared__ int   wi[16];      // per-wave partial argmax (local idx)

    if (t == 0) {
        const float cx = base[0], cy = base[1], cz = base[2];
        ldsC[0] = cx; ldsC[1] = cy; ldsC[2] = cz;
        if (j == 0) {
            float* o = out + (size_t)b * MCENT * 3;
            o[0] = cx; o[1] = cy; o[2] = cz;
        }
    }

    const int wave = t >> 6;
    const int lane = t & 63;

    for (int k = 1; k < MCENT; ++k) {
        __syncthreads();                         // ldsC valid for this iter
        const float cx = ldsC[0], cy = ldsC[1], cz = ldsC[2];

        float bv = -1.0f; int bp = 0;
#pragma unroll
        for (int w = 0; w < WPT; ++w) {
            // bit-exact reference arithmetic (verified R7): subs, then
            // fma(dz,dz, fma(dx,dx, mul(dy,dy)))
            const float dx = __fsub_rn(x[w], cx);
            const float dy = __fsub_rn(y[w], cy);
            const float dz = __fsub_rn(z[w], cz);
            const float s  = __fmaf_rn(dz, dz,
                             __fmaf_rn(dx, dx,
                             __fmul_rn(dy, dy)));
            const float nd = fminf(d[w], s);
            d[w] = nd;
            if (nd > bv) { bv = nd; bp = w * THREADS + t; }
        }

        // wave-level argmax (64 lanes), tie -> smaller index
#pragma unroll
        for (int off = 32; off >= 1; off >>= 1) {
            const float ov = __shfl_down(bv, off);
            const int   oi = __shfl_down(bp, off);
            if (ov > bv || (ov == bv && oi < bp)) { bv = ov; bp = oi; }
        }
        if (lane == 0) { wv[wave] = bv; wi[wave] = bp; }
        __syncthreads();

        if (wave == 0) {
            // cross-wave reduce on lanes 0..15 via shuffle (tie -> smaller idx)
            float pv; int pi;
            if (lane < 16) { pv = wv[lane]; pi = wi[lane]; }
            else           { pv = -1.0f;    pi = 0x7fffffff; }
#pragma unroll
            for (int off = 8; off >= 1; off >>= 1) {
                const float ov = __shfl_down(pv, off);
                const int   oi = __shfl_down(pi, off);
                if (ov > pv || (ov == pv && oi < pi)) { pv = ov; pi = oi; }
            }

            if (lane == 0) {
                // own candidate coords (this block streamed this range -> L2 hit)
                const size_t gp = (size_t)(p0 + pi) * 3;
                const float sx = base[gp + 0];
                const float sy = base[gp + 1];
                const float sz = base[gp + 2];

                unsigned long long* sl =
                    slots + ((size_t)(k & 1) * (NBATCH * BPB) + (size_t)b * BPB) * SLOT_ULL;

                // publish: 4 independent tagged words, fire-and-forget
                __hip_atomic_store(&sl[j * SLOT_ULL + 0], packw(bits_from_f(pv), k, pi),
                                   __ATOMIC_RELAXED, __HIP_MEMORY_SCOPE_AGENT);
                __hip_atomic_store(&sl[j * SLOT_ULL + 1], packw(bits_from_f(sx), k, pi),
                                   __ATOMIC_RELAXED, __HIP_MEMORY_SCOPE_AGENT);
                __hip_atomic_store(&sl[j * SLOT_ULL + 2], packw(bits_from_f(sy), k, pi),
                                   __ATOMIC_RELAXED, __HIP_MEMORY_SCOPE_AGENT);
                __hip_atomic_store(&sl[j * SLOT_ULL + 3], packw(bits_from_f(sz), k, pi),
                                   __ATOMIC_RELAXED, __HIP_MEMORY_SCOPE_AGENT);

                // hot spin until all 4 words of all 8 peers carry tag k
                unsigned long long va[BPB], xa[BPB], ya[BPB], za[BPB];
                bool ok;
                do {
                    ok = true;
#pragma unroll
                    for (int jj = 0; jj < BPB; ++jj) {
                        va[jj] = __hip_atomic_load(&sl[jj * SLOT_ULL + 0],
                                                   __ATOMIC_RELAXED, __HIP_MEMORY_SCOPE_AGENT);
                        xa[jj] = __hip_atomic_load(&sl[jj * SLOT_ULL + 1],
                                                   __ATOMIC_RELAXED, __HIP_MEMORY_SCOPE_AGENT);
                        ya[jj] = __hip_atomic_load(&sl[jj * SLOT_ULL + 2],
                                                   __ATOMIC_RELAXED, __HIP_MEMORY_SCOPE_AGENT);
                        za[jj] = __hip_atomic_load(&sl[jj * SLOT_ULL + 3],
                                                   __ATOMIC_RELAXED, __HIP_MEMORY_SCOPE_AGENT);
                    }
#pragma unroll
                    for (int jj = 0; jj < BPB; ++jj) {
                        const uint32_t kk = (uint32_t)k;
                        ok &= (((uint32_t)va[jj]) >> 16) == kk;
                        ok &= (((uint32_t)xa[jj]) >> 16) == kk;
                        ok &= (((uint32_t)ya[jj]) >> 16) == kk;
                        ok &= (((uint32_t)za[jj]) >> 16) == kk;
                    }
                } while (!ok);

                // global winner; jj ascending + explicit idx -> first occurrence
                float gv = -1.0f; int gidx = 0;
                float gx = 0.0f, gy = 0.0f, gz = 0.0f;
#pragma unroll
                for (int jj = 0; jj < BPB; ++jj) {
                    const float v  = f_from_bits((uint32_t)(va[jj] >> 32));
                    const int   gi = jj * CHUNK + (int)(va[jj] & 0xffffull);
                    if (v > gv || (v == gv && gi < gidx)) {
                        gv = v; gidx = gi;
                        gx = f_from_bits((uint32_t)(xa[jj] >> 32));
                        gy = f_from_bits((uint32_t)(ya[jj] >> 32));
                        gz = f_from_bits((uint32_t)(za[jj] >> 32));
                    }
                }

                ldsC[0] = gx; ldsC[1] = gy; ldsC[2] = gz;
                if (j == 0) {
                    float* o = out + ((size_t)b * MCENT + k) * 3;
                    o[0] = gx; o[1] = gy; o[2] = gz;
                }
            }
        }
    }
}

extern "C" void kernel_launch(void* const* d_in, const int* in_sizes, int n_in,
                              void* d_out, int out_size, void* d_ws, size_t ws_size,
                              hipStream_t stream) {
    const float* xyz = (const float*)d_in[0];
    float* out = (float*)d_out;
    unsigned long long* slots = (unsigned long long*)d_ws; // needs 32 KiB

    fps_kernel<<<dim3(NBATCH * BPB), dim3(THREADS), 0, stream>>>(xyz, out, slots);
}